// Round 1
// baseline (24.938 us; speedup 1.0000x reference)
//
#include <hip/hip_runtime.h>
#include <math.h>

#define NQ 32

// ---------- gate helpers (match reference exactly) ----------
struct Amp { float ar, ai, br, bi; };

__device__ __forceinline__ void g_ry(float c, float s, Amp& v) {
    Amp o;
    o.ar = c * v.ar - s * v.br;
    o.ai = c * v.ai - s * v.bi;
    o.br = s * v.ar + c * v.br;
    o.bi = s * v.ai + c * v.bi;
    v = o;
}
__device__ __forceinline__ void g_rz(float c, float s, Amp& v) {
    Amp o;
    o.ar = c * v.ar + s * v.ai;
    o.ai = c * v.ai - s * v.ar;
    o.br = c * v.br - s * v.bi;
    o.bi = c * v.bi + s * v.br;
    v = o;
}
__device__ __forceinline__ void g_rx(float c, float s, Amp& v) {
    Amp o;
    o.ar = c * v.ar + s * v.bi;
    o.ai = c * v.ai - s * v.br;
    o.br = s * v.ai + c * v.br;
    o.bi = -s * v.ar + c * v.bi;
    v = o;
}

// ---------- precompute per-qubit coefficients K0,K1,K2 ----------
// coeffs layout: [K0[0..31], K1[0..31], K2[0..31]]
__global__ void qc_precompute(const float* __restrict__ params, int L,
                              float* __restrict__ coeffs) {
    int q = threadIdx.x;
    if (q >= NQ) return;
    // Track both columns of U = prod_l RX(p2) RZ(p1) RY(p0)
    Amp e0 = {1.f, 0.f, 0.f, 0.f};  // -> (U00, U10)
    Amp e1 = {0.f, 0.f, 1.f, 0.f};  // -> (U01, U11)
    for (int l = 0; l < L; ++l) {
        float p0 = params[(l * NQ + q) * 3 + 0] * 0.5f;
        float p1 = params[(l * NQ + q) * 3 + 1] * 0.5f;
        float p2 = params[(l * NQ + q) * 3 + 2] * 0.5f;
        float c, s;
        c = cosf(p0); s = sinf(p0);
        g_ry(c, s, e0); g_ry(c, s, e1);
        c = cosf(p1); s = sinf(p1);
        g_rz(c, s, e0); g_rz(c, s, e1);
        c = cosf(p2); s = sinf(p2);
        g_rx(c, s, e0); g_rx(c, s, e1);
    }
    // u0=U00=(e0.ar,e0.ai) u1=U01=(e1.ar,e1.ai)
    // u2=U10=(e0.br,e0.bi) u3=U11=(e1.br,e1.bi)
    float A = (e0.ar * e0.ar + e0.ai * e0.ai) - (e0.br * e0.br + e0.bi * e0.bi);
    float B = (e1.ar * e1.ar + e1.ai * e1.ai) - (e1.br * e1.br + e1.bi * e1.bi);
    float C = 2.f * ((e0.ar * e1.ai - e0.ai * e1.ar) -
                     (e0.br * e1.bi - e0.bi * e1.br));
    coeffs[q]          = 0.5f * (A + B);   // K0
    coeffs[NQ + q]     = 0.5f * (A - B);   // K1
    coeffs[2 * NQ + q] = 0.5f * C;         // K2
}

// ---------- main streaming kernel: out = K0 + K1*cos(x) + K2*sin(x) ----------
__global__ __launch_bounds__(256) void qc_eval(const float* __restrict__ x,
                                               const float* __restrict__ coeffs,
                                               float* __restrict__ out, int n4) {
    __shared__ float sK[3][NQ];
    if (threadIdx.x < 3 * NQ)
        (&sK[0][0])[threadIdx.x] = coeffs[threadIdx.x];
    __syncthreads();

    int i = blockIdx.x * blockDim.x + threadIdx.x;
    if (i >= n4) return;

    float4 xv = reinterpret_cast<const float4*>(x)[i];
    int q = (i * 4) & (NQ - 1);   // NQ % 4 == 0 so a float4 never crosses a row

    float4 o;
    {
        float c = __cosf(xv.x), s = __sinf(xv.x);
        o.x = fmaf(sK[1][q + 0], c, fmaf(sK[2][q + 0], s, sK[0][q + 0]));
    }
    {
        float c = __cosf(xv.y), s = __sinf(xv.y);
        o.y = fmaf(sK[1][q + 1], c, fmaf(sK[2][q + 1], s, sK[0][q + 1]));
    }
    {
        float c = __cosf(xv.z), s = __sinf(xv.z);
        o.z = fmaf(sK[1][q + 2], c, fmaf(sK[2][q + 2], s, sK[0][q + 2]));
    }
    {
        float c = __cosf(xv.w), s = __sinf(xv.w);
        o.w = fmaf(sK[1][q + 3], c, fmaf(sK[2][q + 3], s, sK[0][q + 3]));
    }
    reinterpret_cast<float4*>(out)[i] = o;
}

extern "C" void kernel_launch(void* const* d_in, const int* in_sizes, int n_in,
                              void* d_out, int out_size, void* d_ws, size_t ws_size,
                              hipStream_t stream) {
    const float* x      = (const float*)d_in[0];
    const float* params = (const float*)d_in[1];
    float* out          = (float*)d_out;
    float* coeffs       = (float*)d_ws;   // 96 floats

    int L = in_sizes[1] / (NQ * 3);
    int n = in_sizes[0];                  // B*Q = 8388608
    int n4 = n / 4;

    qc_precompute<<<1, 64, 0, stream>>>(params, L, coeffs);

    int block = 256;
    int grid = (n4 + block - 1) / block;  // 8192
    qc_eval<<<grid, block, 0, stream>>>(x, coeffs, out, n4);
}

// Round 2
// 19.164 us; speedup vs baseline: 1.3013x; 1.3013x over previous
//
#include <hip/hip_runtime.h>
#include <math.h>

#define NQ 32

// ---------- gate helpers (match reference exactly) ----------
struct Amp { float ar, ai, br, bi; };

__device__ __forceinline__ void g_ry(float c, float s, Amp& v) {
    Amp o;
    o.ar = c * v.ar - s * v.br;
    o.ai = c * v.ai - s * v.bi;
    o.br = s * v.ar + c * v.br;
    o.bi = s * v.ai + c * v.bi;
    v = o;
}
__device__ __forceinline__ void g_rz(float c, float s, Amp& v) {
    Amp o;
    o.ar = c * v.ar + s * v.ai;
    o.ai = c * v.ai - s * v.ar;
    o.br = c * v.br - s * v.bi;
    o.bi = c * v.bi + s * v.br;
    v = o;
}
__device__ __forceinline__ void g_rx(float c, float s, Amp& v) {
    Amp o;
    o.ar = c * v.ar + s * v.bi;
    o.ai = c * v.ai - s * v.br;
    o.br = s * v.ai + c * v.br;
    o.bi = -s * v.ar + c * v.bi;
    v = o;
}

// ---------- fused kernel ----------
// Threads 0..31 each compose their qubit's SU(2) product -> K0,K1,K2 in LDS,
// then all threads stream: out = K0[q] + K1[q]*cos(x) + K2[q]*sin(x).
__global__ __launch_bounds__(256) void qc_fused(const float* __restrict__ x,
                                                const float* __restrict__ params,
                                                float* __restrict__ out,
                                                int n4, int L) {
    __shared__ float sK[3][NQ];
    int t = threadIdx.x;
    if (t < NQ) {
        Amp e0 = {1.f, 0.f, 0.f, 0.f};  // column 0 -> (U00, U10)
        Amp e1 = {0.f, 0.f, 1.f, 0.f};  // column 1 -> (U01, U11)
        for (int l = 0; l < L; ++l) {
            float p0 = params[(l * NQ + t) * 3 + 0] * 0.5f;
            float p1 = params[(l * NQ + t) * 3 + 1] * 0.5f;
            float p2 = params[(l * NQ + t) * 3 + 2] * 0.5f;
            float c, s;
            c = __cosf(p0); s = __sinf(p0);
            g_ry(c, s, e0); g_ry(c, s, e1);
            c = __cosf(p1); s = __sinf(p1);
            g_rz(c, s, e0); g_rz(c, s, e1);
            c = __cosf(p2); s = __sinf(p2);
            g_rx(c, s, e0); g_rx(c, s, e1);
        }
        float A = (e0.ar * e0.ar + e0.ai * e0.ai) - (e0.br * e0.br + e0.bi * e0.bi);
        float B = (e1.ar * e1.ar + e1.ai * e1.ai) - (e1.br * e1.br + e1.bi * e1.bi);
        float C = 2.f * ((e0.ar * e1.ai - e0.ai * e1.ar) -
                         (e0.br * e1.bi - e0.bi * e1.br));
        sK[0][t] = 0.5f * (A + B);   // K0
        sK[1][t] = 0.5f * (A - B);   // K1
        sK[2][t] = 0.5f * C;         // K2
    }
    __syncthreads();

    for (int i = blockIdx.x * blockDim.x + threadIdx.x; i < n4;
         i += gridDim.x * blockDim.x) {
        float4 xv = reinterpret_cast<const float4*>(x)[i];
        int q = (i * 4) & (NQ - 1);   // NQ%4==0: a float4 never crosses a row

        float4 o;
        {
            float c = __cosf(xv.x), s = __sinf(xv.x);
            o.x = fmaf(sK[1][q + 0], c, fmaf(sK[2][q + 0], s, sK[0][q + 0]));
        }
        {
            float c = __cosf(xv.y), s = __sinf(xv.y);
            o.y = fmaf(sK[1][q + 1], c, fmaf(sK[2][q + 1], s, sK[0][q + 1]));
        }
        {
            float c = __cosf(xv.z), s = __sinf(xv.z);
            o.z = fmaf(sK[1][q + 2], c, fmaf(sK[2][q + 2], s, sK[0][q + 2]));
        }
        {
            float c = __cosf(xv.w), s = __sinf(xv.w);
            o.w = fmaf(sK[1][q + 3], c, fmaf(sK[2][q + 3], s, sK[0][q + 3]));
        }
        reinterpret_cast<float4*>(out)[i] = o;
    }
}

extern "C" void kernel_launch(void* const* d_in, const int* in_sizes, int n_in,
                              void* d_out, int out_size, void* d_ws, size_t ws_size,
                              hipStream_t stream) {
    const float* x      = (const float*)d_in[0];
    const float* params = (const float*)d_in[1];
    float* out          = (float*)d_out;

    int L  = in_sizes[1] / (NQ * 3);
    int n  = in_sizes[0];             // B*Q = 8388608
    int n4 = n / 4;                   // 2097152 float4 elements

    // 2048 blocks = 8 per CU (all resident); each block grid-strides 4 chunks,
    // so the redundant per-block coefficient precompute is amortized 4x and
    // runs concurrently across all blocks.
    int block = 256;
    int grid  = 2048;
    qc_fused<<<grid, block, 0, stream>>>(x, params, out, n4, L);
}

// Round 3
// 16.919 us; speedup vs baseline: 1.4739x; 1.1327x over previous
//
#include <hip/hip_runtime.h>
#include <math.h>

#define NQ 32

typedef float v4f __attribute__((ext_vector_type(4)));

// ---------- gate helpers (match reference exactly) ----------
struct Amp { float ar, ai, br, bi; };

__device__ __forceinline__ void g_ry(float c, float s, Amp& v) {
    Amp o;
    o.ar = c * v.ar - s * v.br;
    o.ai = c * v.ai - s * v.bi;
    o.br = s * v.ar + c * v.br;
    o.bi = s * v.ai + c * v.bi;
    v = o;
}
__device__ __forceinline__ void g_rz(float c, float s, Amp& v) {
    Amp o;
    o.ar = c * v.ar + s * v.ai;
    o.ai = c * v.ai - s * v.ar;
    o.br = c * v.br - s * v.bi;
    o.bi = c * v.bi + s * v.br;
    v = o;
}
__device__ __forceinline__ void g_rx(float c, float s, Amp& v) {
    Amp o;
    o.ar = c * v.ar + s * v.bi;
    o.ai = c * v.ai - s * v.br;
    o.br = s * v.ai + c * v.br;
    o.bi = -s * v.ar + c * v.bi;
    v = o;
}

// Apply the 3-gate layer (RY, RZ, RX) to both columns.
__device__ __forceinline__ void apply_layer(float t0, float t1, float t2,
                                            Amp& e0, Amp& e1) {
    float c, s;
    __sincosf(t0, &s, &c);
    g_ry(c, s, e0); g_ry(c, s, e1);
    __sincosf(t1, &s, &c);
    g_rz(c, s, e0); g_rz(c, s, e1);
    __sincosf(t2, &s, &c);
    g_rx(c, s, e0); g_rx(c, s, e1);
}

// ---------- fused kernel ----------
// Threads 0..31 compose their qubit's SU(2) product -> K0,K1,K2 in LDS, while
// every thread's first x chunk is already in flight. Then stream:
//   out = K0[q] + K1[q]*cos(x) + K2[q]*sin(x)
// with coefficients hoisted to registers (q is loop-invariant per thread).
template <int LFIX>
__global__ __launch_bounds__(256) void qc_fused(const float* __restrict__ x,
                                                const float* __restrict__ params,
                                                float* __restrict__ out,
                                                int n4, int Lrt) {
    __shared__ float sK[3][NQ];
    const int t = threadIdx.x;
    const int stride = gridDim.x * blockDim.x;
    const v4f* __restrict__ x4 = reinterpret_cast<const v4f*>(x);
    v4f* __restrict__ out4 = reinterpret_cast<v4f*>(out);

    // Prefetch first chunk BEFORE the barrier: HBM fetch overlaps precompute.
    int i = blockIdx.x * blockDim.x + t;
    bool have = i < n4;
    v4f xv = {0.f, 0.f, 0.f, 0.f};
    if (have) xv = __builtin_nontemporal_load(x4 + i);

    if (t < NQ) {
        Amp e0 = {1.f, 0.f, 0.f, 0.f};  // column 0 -> (U00, U10)
        Amp e1 = {0.f, 0.f, 1.f, 0.f};  // column 1 -> (U01, U11)
        if constexpr (LFIX > 0) {
            // Compile-time L: all param loads issued up front (one round-trip).
            float th[LFIX][3];
#pragma unroll
            for (int l = 0; l < LFIX; ++l) {
                th[l][0] = params[(l * NQ + t) * 3 + 0] * 0.5f;
                th[l][1] = params[(l * NQ + t) * 3 + 1] * 0.5f;
                th[l][2] = params[(l * NQ + t) * 3 + 2] * 0.5f;
            }
#pragma unroll
            for (int l = 0; l < LFIX; ++l)
                apply_layer(th[l][0], th[l][1], th[l][2], e0, e1);
        } else {
            for (int l = 0; l < Lrt; ++l) {
                float t0 = params[(l * NQ + t) * 3 + 0] * 0.5f;
                float t1 = params[(l * NQ + t) * 3 + 1] * 0.5f;
                float t2 = params[(l * NQ + t) * 3 + 2] * 0.5f;
                apply_layer(t0, t1, t2, e0, e1);
            }
        }
        float A = (e0.ar * e0.ar + e0.ai * e0.ai) - (e0.br * e0.br + e0.bi * e0.bi);
        float B = (e1.ar * e1.ar + e1.ai * e1.ai) - (e1.br * e1.br + e1.bi * e1.bi);
        float C = 2.f * ((e0.ar * e1.ai - e0.ai * e1.ar) -
                         (e0.br * e1.bi - e0.bi * e1.br));
        sK[0][t] = 0.5f * (A + B);   // K0
        sK[1][t] = 0.5f * (A - B);   // K1
        sK[2][t] = 0.5f * C;         // K2
    }
    __syncthreads();

    // q = (4*global_elem_index) & 31 is loop-invariant: blockDim=256 and the
    // grid stride (in elements) are both multiples of 8 float4s (32 elems).
    const int q = (4 * t) & (NQ - 1);
    const float k0a = sK[0][q + 0], k1a = sK[1][q + 0], k2a = sK[2][q + 0];
    const float k0b = sK[0][q + 1], k1b = sK[1][q + 1], k2b = sK[2][q + 1];
    const float k0c = sK[0][q + 2], k1c = sK[1][q + 2], k2c = sK[2][q + 2];
    const float k0d = sK[0][q + 3], k1d = sK[1][q + 3], k2d = sK[2][q + 3];

    while (have) {
        const int inext = i + stride;
        const bool more = inext < n4;
        v4f xn = {0.f, 0.f, 0.f, 0.f};
        if (more) xn = __builtin_nontemporal_load(x4 + inext);  // pipeline next

        v4f o;
        float s, c;
        __sincosf(xv[0], &s, &c); o[0] = fmaf(k1a, c, fmaf(k2a, s, k0a));
        __sincosf(xv[1], &s, &c); o[1] = fmaf(k1b, c, fmaf(k2b, s, k0b));
        __sincosf(xv[2], &s, &c); o[2] = fmaf(k1c, c, fmaf(k2c, s, k0c));
        __sincosf(xv[3], &s, &c); o[3] = fmaf(k1d, c, fmaf(k2d, s, k0d));
        __builtin_nontemporal_store(o, out4 + i);

        i = inext; xv = xn; have = more;
    }
}

extern "C" void kernel_launch(void* const* d_in, const int* in_sizes, int n_in,
                              void* d_out, int out_size, void* d_ws, size_t ws_size,
                              hipStream_t stream) {
    const float* x      = (const float*)d_in[0];
    const float* params = (const float*)d_in[1];
    float* out          = (float*)d_out;

    int L  = in_sizes[1] / (NQ * 3);
    int n  = in_sizes[0];             // B*Q = 8388608
    int n4 = n / 4;                   // 2097152 float4 chunks

    int block = 256;
    int grid  = 2048;                 // 8 blocks/CU resident; 4 chunks/thread

    if (L == 8)
        qc_fused<8><<<grid, block, 0, stream>>>(x, params, out, n4, L);
    else
        qc_fused<0><<<grid, block, 0, stream>>>(x, params, out, n4, L);
}

// Round 4
// 15.169 us; speedup vs baseline: 1.6440x; 1.1154x over previous
//
#include <hip/hip_runtime.h>
#include <math.h>

#define NQ 32
#define MAXL 16   // LDS staging capacity for params (L <= 16 supported fused)

typedef float v4f __attribute__((ext_vector_type(4)));

// ---------- gate helpers (match reference exactly) ----------
struct Amp { float ar, ai, br, bi; };

__device__ __forceinline__ void g_ry(float c, float s, Amp& v) {
    Amp o;
    o.ar = c * v.ar - s * v.br;
    o.ai = c * v.ai - s * v.bi;
    o.br = s * v.ar + c * v.br;
    o.bi = s * v.ai + c * v.bi;
    v = o;
}
__device__ __forceinline__ void g_rz(float c, float s, Amp& v) {
    Amp o;
    o.ar = c * v.ar + s * v.ai;
    o.ai = c * v.ai - s * v.ar;
    o.br = c * v.br - s * v.bi;
    o.bi = c * v.bi + s * v.br;
    v = o;
}
__device__ __forceinline__ void g_rx(float c, float s, Amp& v) {
    Amp o;
    o.ar = c * v.ar + s * v.bi;
    o.ai = c * v.ai - s * v.br;
    o.br = s * v.ai + c * v.br;
    o.bi = -s * v.ar + c * v.bi;
    v = o;
}

// ---------- fused kernel ----------
// Phase 0 (pre-barrier): all threads issue their 4 x-loads AND cooperatively
//   stage the 3 KB params into LDS (one coalesced round-trip).
// Phase 1: threads 0..31 compose the per-qubit SU(2) product from LDS thetas
//   -> K0,K1,K2 (x loads finishing concurrently).
// Phase 2: out = K0[q] + K1[q]*cos(x) + K2[q]*sin(x), 4 chunks/thread.
__global__ __launch_bounds__(256, 8) void qc_fused(const float* __restrict__ x,
                                                   const float* __restrict__ params,
                                                   float* __restrict__ out,
                                                   int n4, int L) {
    __shared__ float sTh[MAXL * NQ * 3];
    __shared__ float sK[3][NQ];
    const int t = threadIdx.x;
    const int stride = gridDim.x * blockDim.x;
    const v4f* __restrict__ x4 = reinterpret_cast<const v4f*>(x);
    v4f* __restrict__ out4 = reinterpret_cast<v4f*>(out);

    // --- issue all four x loads up front (max MLP, overlaps precompute) ---
    const int i0 = blockIdx.x * blockDim.x + t;
    const int i1 = i0 + stride, i2 = i1 + stride, i3 = i2 + stride;
    const bool h0 = i0 < n4, h1 = i1 < n4, h2 = i2 < n4, h3 = i3 < n4;
    v4f xa = {0,0,0,0}, xb = {0,0,0,0}, xc = {0,0,0,0}, xd = {0,0,0,0};
    if (h0) xa = x4[i0];
    if (h1) xb = x4[i1];
    if (h2) xc = x4[i2];
    if (h3) xd = x4[i3];

    // --- stage params into LDS (3*NQ*L floats, contiguous) ---
    const int nTh4 = (L * NQ * 3) / 4;     // 192 float4s for L=8
    for (int j = t; j < nTh4; j += blockDim.x)
        reinterpret_cast<v4f*>(sTh)[j] = reinterpret_cast<const v4f*>(params)[j];
    __syncthreads();

    // --- per-qubit coefficient precompute from LDS ---
    if (t < NQ) {
        Amp e0 = {1.f, 0.f, 0.f, 0.f};  // column 0 -> (U00, U10)
        Amp e1 = {0.f, 0.f, 1.f, 0.f};  // column 1 -> (U01, U11)
        for (int l = 0; l < L; ++l) {
            const float* th = &sTh[(l * NQ + t) * 3];
            float c, s;
            __sincosf(th[0] * 0.5f, &s, &c);
            g_ry(c, s, e0); g_ry(c, s, e1);
            __sincosf(th[1] * 0.5f, &s, &c);
            g_rz(c, s, e0); g_rz(c, s, e1);
            __sincosf(th[2] * 0.5f, &s, &c);
            g_rx(c, s, e0); g_rx(c, s, e1);
        }
        float A = (e0.ar * e0.ar + e0.ai * e0.ai) - (e0.br * e0.br + e0.bi * e0.bi);
        float B = (e1.ar * e1.ar + e1.ai * e1.ai) - (e1.br * e1.br + e1.bi * e1.bi);
        float C = 2.f * ((e0.ar * e1.ai - e0.ai * e1.ar) -
                         (e0.br * e1.bi - e0.bi * e1.br));
        sK[0][t] = 0.5f * (A + B);   // K0
        sK[1][t] = 0.5f * (A - B);   // K1
        sK[2][t] = 0.5f * C;         // K2
    }
    __syncthreads();

    // q = (4*elem) & 31 is the same for all 4 chunks (stride % 32 == 0).
    const int q = (4 * t) & (NQ - 1);
    const float k0a = sK[0][q + 0], k1a = sK[1][q + 0], k2a = sK[2][q + 0];
    const float k0b = sK[0][q + 1], k1b = sK[1][q + 1], k2b = sK[2][q + 1];
    const float k0c = sK[0][q + 2], k1c = sK[1][q + 2], k2c = sK[2][q + 2];
    const float k0d = sK[0][q + 3], k1d = sK[1][q + 3], k2d = sK[2][q + 3];

#define EVAL(xv, ov)                                                        \
    do {                                                                    \
        float s_, c_;                                                       \
        __sincosf((xv)[0], &s_, &c_); (ov)[0] = fmaf(k1a, c_, fmaf(k2a, s_, k0a)); \
        __sincosf((xv)[1], &s_, &c_); (ov)[1] = fmaf(k1b, c_, fmaf(k2b, s_, k0b)); \
        __sincosf((xv)[2], &s_, &c_); (ov)[2] = fmaf(k1c, c_, fmaf(k2c, s_, k0c)); \
        __sincosf((xv)[3], &s_, &c_); (ov)[3] = fmaf(k1d, c_, fmaf(k2d, s_, k0d)); \
    } while (0)

    v4f o;
    if (h0) { EVAL(xa, o); __builtin_nontemporal_store(o, out4 + i0); }
    if (h1) { EVAL(xb, o); __builtin_nontemporal_store(o, out4 + i1); }
    if (h2) { EVAL(xc, o); __builtin_nontemporal_store(o, out4 + i2); }
    if (h3) { EVAL(xd, o); __builtin_nontemporal_store(o, out4 + i3); }

    // robustness tail (not taken for the benchmarked shape)
    for (int i = i3 + stride; i < n4; i += stride) {
        v4f xv = x4[i];
        EVAL(xv, o);
        __builtin_nontemporal_store(o, out4 + i);
    }
#undef EVAL
}

extern "C" void kernel_launch(void* const* d_in, const int* in_sizes, int n_in,
                              void* d_out, int out_size, void* d_ws, size_t ws_size,
                              hipStream_t stream) {
    const float* x      = (const float*)d_in[0];
    const float* params = (const float*)d_in[1];
    float* out          = (float*)d_out;

    int L  = in_sizes[1] / (NQ * 3);   // 8
    if (L > MAXL) L = MAXL;            // (shape is fixed; guard only)
    int n  = in_sizes[0];              // B*Q = 8388608
    int n4 = n / 4;                    // 2097152 float4 chunks

    int block = 256;
    int grid  = 2048;                  // 2048*256*4 == n4 exactly
    qc_fused<<<grid, block, 0, stream>>>(x, params, out, n4, L);
}

// Round 5
// 13.865 us; speedup vs baseline: 1.7986x; 1.0941x over previous
//
#include <hip/hip_runtime.h>
#include <math.h>

#define NQ 32
#define MAXL 16   // LDS staging capacity for params (L <= 16)

typedef float v4f __attribute__((ext_vector_type(4)));

// ---------- gate helpers (match reference exactly) ----------
struct Amp { float ar, ai, br, bi; };

__device__ __forceinline__ void g_ry(float c, float s, Amp& v) {
    Amp o;
    o.ar = c * v.ar - s * v.br;
    o.ai = c * v.ai - s * v.bi;
    o.br = s * v.ar + c * v.br;
    o.bi = s * v.ai + c * v.bi;
    v = o;
}
__device__ __forceinline__ void g_rz(float c, float s, Amp& v) {
    Amp o;
    o.ar = c * v.ar + s * v.ai;
    o.ai = c * v.ai - s * v.ar;
    o.br = c * v.br - s * v.bi;
    o.bi = c * v.bi + s * v.br;
    v = o;
}
__device__ __forceinline__ void g_rx(float c, float s, Amp& v) {
    Amp o;
    o.ar = c * v.ar + s * v.bi;
    o.ai = c * v.ai - s * v.br;
    o.br = s * v.ai + c * v.br;
    o.bi = -s * v.ar + c * v.bi;
    v = o;
}

// ---------- fused kernel ----------
// Phase 0 (pre-barrier): every thread issues its 4 x-loads; first 192 threads
//   stage the 3 KB params into LDS (one coalesced round-trip).
// Phase 1: wave 0 composes the per-qubit SU(2) product — lanes 0..31 evolve
//   column 0, lanes 32..63 evolve column 1 (same thetas), recombined with
//   4 shfl_xor(32). Lanes 0..31 emit K0, R=sqrt(K1^2+K2^2), phi=atan2(K2,K1).
// Phase 2: out = K0[q] + R[q]*cos(x - phi[q]), 4 float4 chunks/thread.
__global__ __launch_bounds__(1024, 8) void qc_fused(const float* __restrict__ x,
                                                    const float* __restrict__ params,
                                                    float* __restrict__ out,
                                                    int n4, int L) {
    __shared__ float sTh[MAXL * NQ * 3];
    __shared__ float sK0[NQ], sR[NQ], sPh[NQ];
    const int t = threadIdx.x;
    const int stride = gridDim.x * blockDim.x;
    const v4f* __restrict__ x4 = reinterpret_cast<const v4f*>(x);
    v4f* __restrict__ out4 = reinterpret_cast<v4f*>(out);

    // --- issue all four x loads up front (overlaps staging + precompute) ---
    const int i0 = blockIdx.x * blockDim.x + t;
    const int i1 = i0 + stride, i2 = i1 + stride, i3 = i2 + stride;
    const bool h0 = i0 < n4, h1 = i1 < n4, h2 = i2 < n4, h3 = i3 < n4;
    v4f xa = {0,0,0,0}, xb = {0,0,0,0}, xc = {0,0,0,0}, xd = {0,0,0,0};
    if (h0) xa = __builtin_nontemporal_load(x4 + i0);
    if (h1) xb = __builtin_nontemporal_load(x4 + i1);
    if (h2) xc = __builtin_nontemporal_load(x4 + i2);
    if (h3) xd = __builtin_nontemporal_load(x4 + i3);

    // --- stage params into LDS (3*NQ*L floats, contiguous) ---
    const int nTh4 = (L * NQ * 3) / 4;     // 192 float4s for L=8
    if (t < nTh4)
        reinterpret_cast<v4f*>(sTh)[t] = reinterpret_cast<const v4f*>(params)[t];
    __syncthreads();

    // --- per-qubit coefficients: wave 0, columns split across half-waves ---
    if (t < 64) {
        const int q = t & (NQ - 1);
        Amp v;
        if (t < NQ) v = {1.f, 0.f, 0.f, 0.f};   // column 0 -> (U00, U10)
        else        v = {0.f, 0.f, 1.f, 0.f};   // column 1 -> (U01, U11)
        for (int l = 0; l < L; ++l) {
            const float* th = &sTh[(l * NQ + q) * 3];
            float c, s;
            __sincosf(th[0] * 0.5f, &s, &c);
            g_ry(c, s, v);
            __sincosf(th[1] * 0.5f, &s, &c);
            g_rz(c, s, v);
            __sincosf(th[2] * 0.5f, &s, &c);
            g_rx(c, s, v);
        }
        // bring column 1 down to lanes 0..31
        float par = __shfl_xor(v.ar, 32);
        float pai = __shfl_xor(v.ai, 32);
        float pbr = __shfl_xor(v.br, 32);
        float pbi = __shfl_xor(v.bi, 32);
        if (t < NQ) {
            float A = (v.ar * v.ar + v.ai * v.ai) - (v.br * v.br + v.bi * v.bi);
            float B = (par * par + pai * pai) - (pbr * pbr + pbi * pbi);
            float C = 2.f * ((v.ar * pai - v.ai * par) - (v.br * pbi - v.bi * pbr));
            float K0 = 0.5f * (A + B);
            float K1 = 0.5f * (A - B);
            float K2 = 0.5f * C;
            sK0[q] = K0;
            sR[q]  = sqrtf(K1 * K1 + K2 * K2);
            sPh[q] = atan2f(K2, K1);
        }
    }
    __syncthreads();

    // q = (4*elem) & 31 is identical for all 4 chunks (stride % 32 == 0).
    const int q = (4 * t) & (NQ - 1);
    const float k0a = sK0[q + 0], ra = sR[q + 0], pa = sPh[q + 0];
    const float k0b = sK0[q + 1], rb = sR[q + 1], pb = sPh[q + 1];
    const float k0c = sK0[q + 2], rc = sR[q + 2], pc = sPh[q + 2];
    const float k0d = sK0[q + 3], rd = sR[q + 3], pd = sPh[q + 3];

#define EVAL(xv, ov)                                            \
    do {                                                        \
        (ov)[0] = fmaf(ra, __cosf((xv)[0] - pa), k0a);          \
        (ov)[1] = fmaf(rb, __cosf((xv)[1] - pb), k0b);          \
        (ov)[2] = fmaf(rc, __cosf((xv)[2] - pc), k0c);          \
        (ov)[3] = fmaf(rd, __cosf((xv)[3] - pd), k0d);          \
    } while (0)

    v4f o;
    if (h0) { EVAL(xa, o); __builtin_nontemporal_store(o, out4 + i0); }
    if (h1) { EVAL(xb, o); __builtin_nontemporal_store(o, out4 + i1); }
    if (h2) { EVAL(xc, o); __builtin_nontemporal_store(o, out4 + i2); }
    if (h3) { EVAL(xd, o); __builtin_nontemporal_store(o, out4 + i3); }

    // robustness tail (not taken for the benchmarked shape)
    for (int i = i3 + stride; i < n4; i += stride) {
        v4f xv = __builtin_nontemporal_load(x4 + i);
        EVAL(xv, o);
        __builtin_nontemporal_store(o, out4 + i);
    }
#undef EVAL
}

extern "C" void kernel_launch(void* const* d_in, const int* in_sizes, int n_in,
                              void* d_out, int out_size, void* d_ws, size_t ws_size,
                              hipStream_t stream) {
    const float* x      = (const float*)d_in[0];
    const float* params = (const float*)d_in[1];
    float* out          = (float*)d_out;

    int L  = in_sizes[1] / (NQ * 3);   // 8
    if (L > MAXL) L = MAXL;            // shape is fixed; guard only
    int n  = in_sizes[0];              // B*Q = 8388608
    int n4 = n / 4;                    // 2097152 float4 chunks

    int block = 1024;                  // 16 waves/block, 2 blocks/CU resident
    int grid  = 512;                   // 512*1024*4 == n4 exactly
    qc_fused<<<grid, block, 0, stream>>>(x, params, out, n4, L);
}

// Round 6
// 13.673 us; speedup vs baseline: 1.8239x; 1.0140x over previous
//
#include <hip/hip_runtime.h>
#include <math.h>

#define NQ 32

typedef float v4f __attribute__((ext_vector_type(4)));

#define REV  0.15915494309189535f   // 1/(2*pi)
#define HREV 0.07957747154594767f   // 0.5/(2*pi)  (half-angle, revolutions)

// SU(2) matrix [[a, -conj(b)], [b, conj(a)]] as (ar,ai,br,bi)
struct SU2 { float ar, ai, br, bi; };

// One layer: U = RX(t2) * RZ(t1) * RY(t0). Closed form (verified against the
// reference gate algebra):
//   a = ( c2c0c1 + s2s0s1,  -(c2c0s1 + s2s0c1) )
//   b = ( c2s0c1 - s2c0s1,   c2s0s1 - s2c0c1  )
__device__ __forceinline__ SU2 build_layer(float th0, float th1, float th2) {
    float c0 = __builtin_amdgcn_cosf(th0 * HREV), s0 = __builtin_amdgcn_sinf(th0 * HREV);
    float c1 = __builtin_amdgcn_cosf(th1 * HREV), s1 = __builtin_amdgcn_sinf(th1 * HREV);
    float c2 = __builtin_amdgcn_cosf(th2 * HREV), s2 = __builtin_amdgcn_sinf(th2 * HREV);
    float tcc = c2 * c0, tss = s2 * s0, tcs = c2 * s0, tsc = s2 * c0;
    SU2 u;
    u.ar =  fmaf(tcc, c1,  tss * s1);
    u.ai = -fmaf(tcc, s1,  tss * c1);
    u.br =  fmaf(tcs, c1, -tsc * s1);
    u.bi =  fmaf(tcs, s1, -tsc * c1);
    return u;
}

// r = H * L (SU(2) composition: a' = ha*la - conj(hb)*lb ; b' = hb*la + conj(ha)*lb)
__device__ __forceinline__ SU2 su2_mul(SU2 H, SU2 L) {
    SU2 r;
    r.ar = H.ar*L.ar - H.ai*L.ai - H.br*L.br - H.bi*L.bi;
    r.ai = H.ar*L.ai + H.ai*L.ar - H.br*L.bi + H.bi*L.br;
    r.br = H.br*L.ar - H.bi*L.ai + H.ar*L.br + H.ai*L.bi;
    r.bi = H.br*L.ai + H.bi*L.ar + H.ar*L.bi - H.ai*L.br;
    return r;
}

// From the total product U: K1 = |a|^2-|b|^2, K2 = 2*Im(a*b); K0 == 0 exactly
// (unitarity). out = R*cos(x - phi), phase stored in revolutions.
__device__ __forceinline__ void emit_coeffs(SU2 m, int q, float* sR, float* sP) {
    float K1 = m.ar*m.ar + m.ai*m.ai - m.br*m.br - m.bi*m.bi;
    float K2 = 2.f * fmaf(m.ar, m.bi, m.ai * m.br);
    sR[q] = sqrtf(fmaf(K1, K1, K2 * K2));
    sP[q] = atan2f(K2, K1) * REV;
}

// ---------- fused kernel ----------
// Phase 0: every thread issues its 4 x-loads (overlaps everything below).
// Phase 1: waves 0-3 (t<256): lane = layer(0-7) x qubit-octet. Each lane
//   builds its layer's SU(2) in closed form, then 3 shfl_xor steps compose
//   the ordered product U7*...*U0. Layer-0 lanes emit R,phi to LDS.
// Phase 2: out = R[q] * cos(x - phi[q]), 4 float4 chunks/thread.
__global__ __launch_bounds__(1024, 8) void qc_fused(const float* __restrict__ x,
                                                    const float* __restrict__ params,
                                                    float* __restrict__ out,
                                                    int n4, int L) {
    __shared__ float sR[NQ], sP[NQ];
    const int t = threadIdx.x;
    const int stride = gridDim.x * blockDim.x;
    const v4f* __restrict__ x4 = reinterpret_cast<const v4f*>(x);
    v4f* __restrict__ out4 = reinterpret_cast<v4f*>(out);

    // --- issue all four x loads up front ---
    const int i0 = blockIdx.x * blockDim.x + t;
    const int i1 = i0 + stride, i2 = i1 + stride, i3 = i2 + stride;
    const bool h0 = i0 < n4, h1 = i1 < n4, h2 = i2 < n4, h3 = i3 < n4;
    v4f xa = {0,0,0,0}, xb = {0,0,0,0}, xc = {0,0,0,0}, xd = {0,0,0,0};
    if (h0) xa = __builtin_nontemporal_load(x4 + i0);
    if (h1) xb = __builtin_nontemporal_load(x4 + i1);
    if (h2) xc = __builtin_nontemporal_load(x4 + i2);
    if (h3) xd = __builtin_nontemporal_load(x4 + i3);

    if (L == 8) {
        // --- tree precompute: 4 waves, 8 layer-lanes x 8 qubits each ---
        if (t < 256) {
            const int l   = t & 63;
            const int lay = l & 7;
            const int q   = ((t >> 6) << 3) + (l >> 3);
            const float* th = params + (lay * NQ + q) * 3;
            SU2 m = build_layer(th[0], th[1], th[2]);
#pragma unroll
            for (int d = 1; d <= 4; d <<= 1) {
                SU2 p;
                p.ar = __shfl_xor(m.ar, d);
                p.ai = __shfl_xor(m.ai, d);
                p.br = __shfl_xor(m.br, d);
                p.bi = __shfl_xor(m.bi, d);
                const bool hi = (lay & d) != 0;   // my half holds the HIGHER layers
                SU2 H, Lo;
                H.ar  = hi ? m.ar : p.ar;  H.ai  = hi ? m.ai : p.ai;
                H.br  = hi ? m.br : p.br;  H.bi  = hi ? m.bi : p.bi;
                Lo.ar = hi ? p.ar : m.ar;  Lo.ai = hi ? p.ai : m.ai;
                Lo.br = hi ? p.br : m.br;  Lo.bi = hi ? p.bi : m.bi;
                m = su2_mul(H, Lo);
            }
            if (lay == 0) emit_coeffs(m, q, sR, sP);
        }
    } else {
        // --- generic-L fallback: serial SU(2) chain, one lane per qubit ---
        if (t < NQ) {
            SU2 m = {1.f, 0.f, 0.f, 0.f};
            for (int l = 0; l < L; ++l) {
                const float* th = params + (l * NQ + t) * 3;
                m = su2_mul(build_layer(th[0], th[1], th[2]), m);
            }
            emit_coeffs(m, t, sR, sP);
        }
    }
    __syncthreads();

    // q = (4*elem) & 31 is identical for all 4 chunks (stride % 32 == 0).
    const int q = (4 * t) & (NQ - 1);
    const float ra = sR[q + 0], pa = sP[q + 0];
    const float rb = sR[q + 1], pb = sP[q + 1];
    const float rc = sR[q + 2], pc = sP[q + 2];
    const float rd = sR[q + 3], pd = sP[q + 3];

#define EVAL(xv, ov)                                                      \
    do {                                                                  \
        (ov)[0] = ra * __builtin_amdgcn_cosf(fmaf((xv)[0], REV, -pa));    \
        (ov)[1] = rb * __builtin_amdgcn_cosf(fmaf((xv)[1], REV, -pb));    \
        (ov)[2] = rc * __builtin_amdgcn_cosf(fmaf((xv)[2], REV, -pc));    \
        (ov)[3] = rd * __builtin_amdgcn_cosf(fmaf((xv)[3], REV, -pd));    \
    } while (0)

    v4f o;
    if (h0) { EVAL(xa, o); __builtin_nontemporal_store(o, out4 + i0); }
    if (h1) { EVAL(xb, o); __builtin_nontemporal_store(o, out4 + i1); }
    if (h2) { EVAL(xc, o); __builtin_nontemporal_store(o, out4 + i2); }
    if (h3) { EVAL(xd, o); __builtin_nontemporal_store(o, out4 + i3); }

    // robustness tail (not taken for the benchmarked shape)
    for (int i = i3 + stride; i < n4; i += stride) {
        v4f xv = __builtin_nontemporal_load(x4 + i);
        EVAL(xv, o);
        __builtin_nontemporal_store(o, out4 + i);
    }
#undef EVAL
}

extern "C" void kernel_launch(void* const* d_in, const int* in_sizes, int n_in,
                              void* d_out, int out_size, void* d_ws, size_t ws_size,
                              hipStream_t stream) {
    const float* x      = (const float*)d_in[0];
    const float* params = (const float*)d_in[1];
    float* out          = (float*)d_out;

    int L  = in_sizes[1] / (NQ * 3);   // 8
    int n  = in_sizes[0];              // B*Q = 8388608
    int n4 = n / 4;                    // 2097152 float4 chunks

    int block = 1024;                  // 16 waves/block, 2 blocks/CU resident
    int grid  = 512;                   // 512*1024*4 == n4 exactly
    qc_fused<<<grid, block, 0, stream>>>(x, params, out, n4, L);
}